// Round 2
// baseline (993.193 us; speedup 1.0000x reference)
//
#include <hip/hip_runtime.h>

#define N_NODES 20000
#define N_EDGES 5000
#define FT 128
#define NSTRIDE 128   // max node degree: Binomial(5000,0.01) = 50 +/- 7; 128 = 11 sd

// Pass 1: one wave per H row (20 KB, coalesced float4 loads).
//  - node_ell / node_cnt built with ballot prefix sums: NO atomics in row direction.
//  - P[e][:] += X[n][:] scattered with fire-and-forget fp32 atomics (no return
//    value -> no dependent latency chain), wave-uniform loop over ballot mask.
//  - edge_cnt[e] += 1 per nnz (fire-and-forget, compacted lanes).
__global__ __launch_bounds__(256) void build_scatter(
    const float4* __restrict__ H4, const float* __restrict__ X,
    int* __restrict__ edge_cnt, float* __restrict__ P,
    int* __restrict__ node_cnt, int* __restrict__ node_ell) {
  const int wid  = threadIdx.x >> 6;
  const int lane = threadIdx.x & 63;
  const int n = blockIdx.x * 4 + wid;           // grid = 5000 blocks -> n < 20000

  const float x0 = X[n * FT + lane];            // X row staged in registers
  const float x1 = X[n * FT + 64 + lane];
  const unsigned long long lt = (1ull << lane) - 1ull;

  const int row4 = n * (N_EDGES / 4);           // 1250 float4 per row
  int* nl = node_ell + n * NSTRIDE;
  int running = 0;

  for (int it = 0; it < 20; ++it) {
    int idx4 = it * 64 + lane;
    float4 v;
    if (idx4 < N_EDGES / 4) v = H4[row4 + idx4];
    else                    v = make_float4(0.f, 0.f, 0.f, 0.f);

    unsigned long long m0 = __ballot(v.x != 0.f);
    unsigned long long m1 = __ballot(v.y != 0.f);
    unsigned long long m2 = __ballot(v.z != 0.f);
    unsigned long long m3 = __ballot(v.w != 0.f);
    if ((m0 | m1 | m2 | m3) == 0ull) continue;  // wave-uniform skip (~8% of chunks)

    int t0 = __popcll(m0), t1 = __popcll(m1), t2 = __popcll(m2), t3 = __popcll(m3);
    int c0 = it * 256;
    int ebase = c0 + lane * 4;

    // per-lane compacted node-list writes + edge counts (fire-and-forget)
    if (v.x != 0.f) { int s = running + __popcll(m0 & lt);
      if (s < NSTRIDE) nl[s] = ebase;     atomicAdd(&edge_cnt[ebase], 1); }
    if (v.y != 0.f) { int s = running + t0 + __popcll(m1 & lt);
      if (s < NSTRIDE) nl[s] = ebase + 1; atomicAdd(&edge_cnt[ebase + 1], 1); }
    if (v.z != 0.f) { int s = running + t0 + t1 + __popcll(m2 & lt);
      if (s < NSTRIDE) nl[s] = ebase + 2; atomicAdd(&edge_cnt[ebase + 2], 1); }
    if (v.w != 0.f) { int s = running + t0 + t1 + t2 + __popcll(m3 & lt);
      if (s < NSTRIDE) nl[s] = ebase + 3; atomicAdd(&edge_cnt[ebase + 3], 1); }
    running += t0 + t1 + t2 + t3;

    // wave-uniform scatter: all 64 lanes add X row into P row e
    unsigned long long mm;
    mm = m0; while (mm) { int l = __ffsll((unsigned long long)mm) - 1; mm &= mm - 1;
      int e = c0 + l * 4;
      atomicAdd(&P[e * FT + lane], x0); atomicAdd(&P[e * FT + 64 + lane], x1); }
    mm = m1; while (mm) { int l = __ffsll((unsigned long long)mm) - 1; mm &= mm - 1;
      int e = c0 + l * 4 + 1;
      atomicAdd(&P[e * FT + lane], x0); atomicAdd(&P[e * FT + 64 + lane], x1); }
    mm = m2; while (mm) { int l = __ffsll((unsigned long long)mm) - 1; mm &= mm - 1;
      int e = c0 + l * 4 + 2;
      atomicAdd(&P[e * FT + lane], x0); atomicAdd(&P[e * FT + 64 + lane], x1); }
    mm = m3; while (mm) { int l = __ffsll((unsigned long long)mm) - 1; mm &= mm - 1;
      int e = c0 + l * 4 + 3;
      atomicAdd(&P[e * FT + lane], x0); atomicAdd(&P[e * FT + 64 + lane], x1); }
  }
  if (lane == 0) node_cnt[n] = running;
}

// Pass 2: M[e][f] = (P[e][:] . W[:][f]) / DE[e].  16 edges/block, 4-edge ILP
// sharing each W load; P loads are wave-uniform broadcasts (L1/L2-hot).
__global__ __launch_bounds__(256) void gemm_M(
    const float* __restrict__ P, const float* __restrict__ W,
    const int* __restrict__ edge_cnt, float* __restrict__ M) {
  int f = threadIdx.x & (FT - 1);
  int half = threadIdx.x >> 7;                  // wave-uniform (waves 0,1 vs 2,3)
  int base = blockIdx.x * 16 + half * 8;
#pragma unroll
  for (int g = 0; g < 8; g += 4) {
    int e = base + g;
    if (e >= N_EDGES) break;                    // N_EDGES % 4 == 0: group all-valid
    const float* p0 = P + (e + 0) * FT;
    const float* p1 = P + (e + 1) * FT;
    const float* p2 = P + (e + 2) * FT;
    const float* p3 = P + (e + 3) * FT;
    float a0 = 0.f, a1 = 0.f, a2 = 0.f, a3 = 0.f;
#pragma unroll 4
    for (int k = 0; k < FT; ++k) {
      float w = W[k * FT + f];
      a0 += p0[k] * w; a1 += p1[k] * w; a2 += p2[k] * w; a3 += p3[k] * w;
    }
    M[(e + 0) * FT + f] = a0 / ((float)edge_cnt[e + 0] + 1e-12f);
    M[(e + 1) * FT + f] = a1 / ((float)edge_cnt[e + 1] + 1e-12f);
    M[(e + 2) * FT + f] = a2 / ((float)edge_cnt[e + 2] + 1e-12f);
    M[(e + 3) * FT + f] = a3 / ((float)edge_cnt[e + 3] + 1e-12f);
  }
}

// Pass 3: wave per node; lane holds 2 features (float2) so ONE wave-load reads a
// full 512 B M row. 8 rows in flight per iteration via int4 index loads.
__global__ __launch_bounds__(256) void node_gather(
    const float2* __restrict__ M2, const int* __restrict__ node_ell,
    const int* __restrict__ node_cnt, const float2* __restrict__ bias2,
    float2* __restrict__ out2) {
  const int wid  = threadIdx.x >> 6;
  const int lane = threadIdx.x & 63;
  const int n = blockIdx.x * 4 + wid;           // grid = 5000 -> n < 20000

  int cnt0 = node_cnt[n];
  int cnt = cnt0 > NSTRIDE ? NSTRIDE : cnt0;
  const int* lst = node_ell + n * NSTRIDE;

  float sx = 0.f, sy = 0.f;
  int j = 0;
  for (; j + 8 <= cnt; j += 8) {
    int4 ia = *(const int4*)(lst + j);
    int4 ib = *(const int4*)(lst + j + 4);
    float2 v0 = M2[ia.x * 64 + lane];
    float2 v1 = M2[ia.y * 64 + lane];
    float2 v2 = M2[ia.z * 64 + lane];
    float2 v3 = M2[ia.w * 64 + lane];
    float2 v4 = M2[ib.x * 64 + lane];
    float2 v5 = M2[ib.y * 64 + lane];
    float2 v6 = M2[ib.z * 64 + lane];
    float2 v7 = M2[ib.w * 64 + lane];
    sx += (v0.x + v1.x) + (v2.x + v3.x) + (v4.x + v5.x) + (v6.x + v7.x);
    sy += (v0.y + v1.y) + (v2.y + v3.y) + (v4.y + v5.y) + (v6.y + v7.y);
  }
  for (; j < cnt; ++j) {
    float2 v = M2[lst[j] * 64 + lane];
    sx += v.x; sy += v.y;
  }
  float inv = 1.f / ((float)cnt0 + 1e-12f);
  float2 b = bias2[lane];
  float2 o;
  o.x = fmaxf(sx * inv + b.x, 0.f);
  o.y = fmaxf(sy * inv + b.y, 0.f);
  out2[n * 64 + lane] = o;
}

extern "C" void kernel_launch(void* const* d_in, const int* in_sizes, int n_in,
                              void* d_out, int out_size, void* d_ws, size_t ws_size,
                              hipStream_t stream) {
  const float* X    = (const float*)d_in[0];   // [20000, 128]
  const float* H    = (const float*)d_in[1];   // [20000, 5000] dense 0/1
  const float* W    = (const float*)d_in[2];   // [128, 128]
  const float* bias = (const float*)d_in[3];   // [128]
  float* out = (float*)d_out;                  // [20000, 128] fp32

  // Workspace (4-byte elems), ~15.5 MB total:
  int* ws       = (int*)d_ws;
  int* edge_cnt = ws;                              // [0, 5120)
  float* P      = (float*)(ws + 5120);             // [5120, 645120)   5000*128
  int* node_cnt = ws + 645120;                     // [645120, 665120)
  int* node_ell = ws + 665120;                     // [665120, 3225120) 20000*128
  float* M      = (float*)(ws + 3225120);          // [3225120, 3865120)

  // Zero only the atomic targets: edge_cnt + P (contiguous, ~2.58 MB).
  hipMemsetAsync(edge_cnt, 0, (size_t)(5120 + N_EDGES * FT) * sizeof(int), stream);

  build_scatter<<<N_NODES / 4, 256, 0, stream>>>((const float4*)H, X, edge_cnt, P,
                                                 node_cnt, node_ell);
  gemm_M<<<(N_EDGES + 15) / 16, 256, 0, stream>>>(P, W, edge_cnt, M);
  node_gather<<<N_NODES / 4, 256, 0, stream>>>((const float2*)M, node_ell, node_cnt,
                                               (const float2*)bias, (float2*)out);
}

// Round 3
// 690.333 us; speedup vs baseline: 1.4387x; 1.4387x over previous
//
#include <hip/hip_runtime.h>
#include <hip/hip_bf16.h>

#define N_NODES 20000
#define N_EDGES 5000
#define FT 128
#define CH_ROWS 320          // rows per chunk (5 x 64)
#define N_CHUNKS 63          // ceil(20000/320), last chunk = 160 rows
#define N_PANELS 79          // ceil(5000/64), last panel = 8 valid cols
#define SEG 24               // per-(edge,chunk) capacity: Poisson(3.2), P(>=24) ~ 1e-13
#define SEG_STRIDE 1536      // 63*24 = 1512 padded to 1536
#define MAX_DEG 320          // edge degree cap: Binomial(20000,.01) = 200 +/- 14 (8.5 sd)

// ---------------------------------------------------------------------------
// Pass 0: X fp32 -> bf16 (halves gather traffic in pass 2; 5 MB => L2-resident)
__global__ __launch_bounds__(256) void x_to_bf16(
    const float2* __restrict__ X2, __hip_bfloat162* __restrict__ Xb2) {
  int i = blockIdx.x * 256 + threadIdx.x;      // grid exactly covers 1,280,000
  Xb2[i] = __float22bfloat162_rn(X2[i]);
}

// ---------------------------------------------------------------------------
// Pass 1: column-panel scan of H (the ONLY 400 MB read).
// Wave = (64-col panel, 320-row chunk). Lane owns one column:
//  - private append of row-ids -> seg[e][chunk][*]  (no atomics)
//  - per-(e,chunk) counts -> scnt                   (no atomics)
//  - ballot per row -> bitmask Hbt[panel][row] so H is never re-read.
__global__ __launch_bounds__(256) void scan_cols(
    const float* __restrict__ H,
    int* __restrict__ seg,                     // [5056][SEG_STRIDE]
    int* __restrict__ scnt,                    // [5056][64]
    unsigned long long* __restrict__ Hbt) {    // [N_PANELS][N_NODES]
  const int wid = threadIdx.x >> 6, lane = threadIdx.x & 63;
  const int panel = (blockIdx.x % 20) * 4 + wid;
  const int chunk = blockIdx.x / 20;
  if (panel >= N_PANELS) return;               // no __syncthreads in kernel: safe
  const int c = panel * 64 + lane;
  const bool cvalid = c < N_EDGES;
  const int r0 = chunk * CH_ROWS;
  const int rend = min(r0 + CH_ROWS, N_NODES); // 320 or 160 (both % 8 == 0)

  int* myseg = seg + c * SEG_STRIDE + chunk * SEG;
  unsigned long long* hb = Hbt + (size_t)panel * N_NODES;
  int cnt = 0;
  unsigned long long msk = 0ull;

  for (int rb = r0; rb < rend; rb += 8) {      // 8 rows => 8 x 256B loads in flight
    float v[8];
    const float* base = H + (size_t)rb * N_EDGES + c;
#pragma unroll
    for (int k = 0; k < 8; ++k) v[k] = 0.f;
    if (cvalid) {
#pragma unroll
      for (int k = 0; k < 8; ++k) v[k] = base[(size_t)k * N_EDGES];
    }
#pragma unroll
    for (int k = 0; k < 8; ++k) {
      int r = rb + k;
      unsigned long long bal = __ballot(v[k] != 0.f);
      msk = ((r & 63) == lane) ? bal : msk;    // lane (r&63) keeps row r's mask
      if (((r & 63) == 63) || (r == N_NODES - 1)) {   // wave-uniform flush
        int g0 = r & ~63;
        if (g0 + lane < N_NODES) hb[g0 + lane] = msk; // coalesced 512B store
        msk = 0ull;
      }
      if (v[k] != 0.f) {
        if (cnt < SEG) myseg[cnt] = r;
        ++cnt;
      }
    }
  }
  if (cvalid) scnt[c * 64 + chunk] = (cnt > SEG) ? SEG : cnt;
}

// ---------------------------------------------------------------------------
// Pass 2: P[e][:] = sum_{n in e} X[n][:], de[e] = |e|. Wave per edge.
// Indices compacted into LDS (shfl prefix scan), then 8 gathers in flight.
__global__ __launch_bounds__(256) void edge_gather(
    const __hip_bfloat162* __restrict__ Xb2,   // [20000][64]
    const int* __restrict__ seg, const int* __restrict__ scnt,
    float2* __restrict__ P2, int* __restrict__ de) {
  __shared__ int sidx[4][MAX_DEG];             // 5 KB
  const int wid = threadIdx.x >> 6, lane = threadIdx.x & 63;
  const int e = blockIdx.x * 4 + wid;          // grid 1250 -> e < 5000

  int cl = (lane < N_CHUNKS) ? scnt[e * 64 + lane] : 0;  // coalesced
  cl = min(cl, SEG);
  // exclusive prefix scan of cl over lanes
  int off = cl;
  for (int d = 1; d < 64; d <<= 1) {
    int t = __shfl_up(off, d);
    if (lane >= d) off += t;
  }
  int total = __shfl(off, 63);
  off -= cl;
  // lane (=chunk) copies its row-ids into the compacted LDS list
  if (cl > 0) {
    const int* sb = seg + e * SEG_STRIDE + lane * SEG;
    for (int i = 0; i < cl; ++i) {
      int o = off + i;
      if (o < MAX_DEG) sidx[wid][o] = sb[i];
    }
  }
  __builtin_amdgcn_s_waitcnt(0);               // drain ds_write before ds_read (wave-local)
  int t = min(total, MAX_DEG);

  float sx = 0.f, sy = 0.f;
  int g = 0;
  for (; g + 8 <= t; g += 8) {                 // 8 x 256B gathers in flight
    int n0 = sidx[wid][g + 0], n1 = sidx[wid][g + 1];
    int n2 = sidx[wid][g + 2], n3 = sidx[wid][g + 3];
    int n4 = sidx[wid][g + 4], n5 = sidx[wid][g + 5];
    int n6 = sidx[wid][g + 6], n7 = sidx[wid][g + 7];
    float2 a0 = __bfloat1622float2(Xb2[n0 * 64 + lane]);
    float2 a1 = __bfloat1622float2(Xb2[n1 * 64 + lane]);
    float2 a2 = __bfloat1622float2(Xb2[n2 * 64 + lane]);
    float2 a3 = __bfloat1622float2(Xb2[n3 * 64 + lane]);
    float2 a4 = __bfloat1622float2(Xb2[n4 * 64 + lane]);
    float2 a5 = __bfloat1622float2(Xb2[n5 * 64 + lane]);
    float2 a6 = __bfloat1622float2(Xb2[n6 * 64 + lane]);
    float2 a7 = __bfloat1622float2(Xb2[n7 * 64 + lane]);
    sx += (a0.x + a1.x) + (a2.x + a3.x) + (a4.x + a5.x) + (a6.x + a7.x);
    sy += (a0.y + a1.y) + (a2.y + a3.y) + (a4.y + a5.y) + (a6.y + a7.y);
  }
  for (; g < t; ++g) {
    float2 a = __bfloat1622float2(Xb2[sidx[wid][g] * 64 + lane]);
    sx += a.x; sy += a.y;
  }
  P2[e * 64 + lane] = make_float2(sx, sy);     // features (2*lane, 2*lane+1)
  if (lane == 0) de[e] = total;
}

// ---------------------------------------------------------------------------
// Pass 3: M[e][f] = (P[e][:] . W[:][f]) / DE[e]. (unchanged from R2 - proven)
__global__ __launch_bounds__(256) void gemm_M(
    const float* __restrict__ P, const float* __restrict__ W,
    const int* __restrict__ de, float* __restrict__ M) {
  int f = threadIdx.x & (FT - 1);
  int half = threadIdx.x >> 7;
  int base = blockIdx.x * 16 + half * 8;
#pragma unroll
  for (int g = 0; g < 8; g += 4) {
    int e = base + g;
    if (e >= N_EDGES) break;
    const float* p0 = P + (e + 0) * FT;
    const float* p1 = P + (e + 1) * FT;
    const float* p2 = P + (e + 2) * FT;
    const float* p3 = P + (e + 3) * FT;
    float a0 = 0.f, a1 = 0.f, a2 = 0.f, a3 = 0.f;
#pragma unroll 4
    for (int k = 0; k < FT; ++k) {
      float w = W[k * FT + f];
      a0 += p0[k] * w; a1 += p1[k] * w; a2 += p2[k] * w; a3 += p3[k] * w;
    }
    M[(e + 0) * FT + f] = a0 / ((float)de[e + 0] + 1e-12f);
    M[(e + 1) * FT + f] = a1 / ((float)de[e + 1] + 1e-12f);
    M[(e + 2) * FT + f] = a2 / ((float)de[e + 2] + 1e-12f);
    M[(e + 3) * FT + f] = a3 / ((float)de[e + 3] + 1e-12f);
  }
}

// ---------------------------------------------------------------------------
// Pass 4: out[n][:] = relu( (sum_{e: H[n][e]=1} M[e][:]) / DV[n] + bias ).
// Wave per row; H re-read replaced by the 12.8 MB bitmask; M is L2-resident.
__global__ __launch_bounds__(256) void row_apply(
    const unsigned long long* __restrict__ Hbt,  // [N_PANELS][N_NODES]
    const float2* __restrict__ M2,               // [5000][64]
    const float2* __restrict__ bias2,
    float2* __restrict__ out2) {
  const int wid = threadIdx.x >> 6, lane = threadIdx.x & 63;
  const int n = blockIdx.x * 4 + wid;            // grid 5000 -> n < 20000

  unsigned long long m0 = Hbt[(size_t)lane * N_NODES + n];               // panels 0..63
  unsigned long long m1 = (lane < N_PANELS - 64)
      ? Hbt[(size_t)(64 + lane) * N_NODES + n] : 0ull;                   // panels 64..78
  float sx = 0.f, sy = 0.f;
  int dv = 0;
  for (int p = 0; p < N_PANELS; ++p) {
    unsigned long long mp = (p < 64) ? __shfl(m0, p) : __shfl(m1, p - 64);
    if (mp == 0ull) continue;                    // wave-uniform skip (~54% of panels)
    dv += __popcll(mp);
    int ebase = p * 64;
    while (mp) {
      int b = __ffsll(mp) - 1;
      mp &= mp - 1;
      float2 mv = M2[(ebase + b) * 64 + lane];   // 512B wave-load, L2-hot
      sx += mv.x; sy += mv.y;
    }
  }
  float inv = 1.f / ((float)dv + 1e-12f);
  float2 bb = bias2[lane];
  float2 o;
  o.x = fmaxf(fmaf(sx, inv, bb.x), 0.f);
  o.y = fmaxf(fmaf(sy, inv, bb.y), 0.f);
  out2[n * 64 + lane] = o;
}

extern "C" void kernel_launch(void* const* d_in, const int* in_sizes, int n_in,
                              void* d_out, int out_size, void* d_ws, size_t ws_size,
                              hipStream_t stream) {
  const float* X    = (const float*)d_in[0];   // [20000, 128]
  const float* H    = (const float*)d_in[1];   // [20000, 5000] dense 0/1
  const float* W    = (const float*)d_in[2];   // [128, 128]
  const float* bias = (const float*)d_in[3];   // [128]
  float* out = (float*)d_out;                  // [20000, 128] fp32

  // Workspace layout (int units). Every location read is written first -> no memset.
  int* ws = (int*)d_ws;
  int* seg                 = ws;                               // 5056*1536 = 7,766,016
  int* scnt                = ws + 7766016;                     // 5056*64   =   323,584
  unsigned long long* Hbt  = (unsigned long long*)(ws + 8089600); // 79*20000 u64 (3,160,000 ints)
  __hip_bfloat162* Xb2     = (__hip_bfloat162*)(ws + 11249600);   // 1,280,000 ints
  float* P                 = (float*)(ws + 12529600);             // 640,000
  int* de                  = ws + 13169600;                       // 5,120
  float* M                 = (float*)(ws + 13174720);             // 640,000  (~55 MB total)

  x_to_bf16 <<<5000, 256, 0, stream>>>((const float2*)X, Xb2);
  scan_cols <<<20 * N_CHUNKS, 256, 0, stream>>>(H, seg, scnt, Hbt);
  edge_gather<<<N_EDGES / 4, 256, 0, stream>>>(Xb2, seg, scnt, (float2*)P, de);
  gemm_M    <<<(N_EDGES + 15) / 16, 256, 0, stream>>>(P, W, de, M);
  row_apply <<<N_NODES / 4, 256, 0, stream>>>(Hbt, (const float2*)M,
                                              (const float2*)bias, (float2*)out);
}